// Round 7
// baseline (2961.611 us; speedup 1.0000x reference)
//
#include <hip/hip_runtime.h>
#include <math.h>

#define Bn 4
#define Ln 4096
#define Dn 1024
#define DIn 4096
#define Mn 8
#define Rn (Bn*Ln)          // 16384 rows
#define CHUNK 4096
#define NCH (Rn/CHUNK)      // 4 chunks
#define NSTEP 4
#define THRc 0.5f
#define EPSc 1e-6f
#define LCH 32              // L-chunks for memory partials
#define LSUB (Ln/LCH)       // 128

typedef unsigned short bfu;
typedef _Float16 f16;
typedef __attribute__((ext_vector_type(8))) _Float16 f16x8;  // MFMA A/B frag (4 VGPRs)
typedef __attribute__((ext_vector_type(4))) _Float16 f16x4;
typedef __attribute__((ext_vector_type(4))) float f32x4;     // MFMA C/D frag

// ---------- helpers ----------
__device__ __forceinline__ bfu f2b(float f) {
    union { float f; unsigned i; } v; v.f = f;
    unsigned r = v.i + 0x7FFFu + ((v.i >> 16) & 1u);  // RNE
    return (bfu)(r >> 16);
}
__device__ __forceinline__ float b2f(bfu u) {
    union { float f; unsigned i; } v; v.i = ((unsigned)u) << 16; return v.f;
}

template<int N>
__device__ __forceinline__ void waitv() {
    asm volatile("s_waitcnt vmcnt(%0)" :: "i"(N) : "memory");
}
__device__ __forceinline__ void block_bar() {
    __builtin_amdgcn_s_barrier();
    __builtin_amdgcn_sched_barrier(0);
}

// ---------- block-wide reductions (block = 256 = 4 waves) ----------
__device__ __forceinline__ float bsum(float v, float* sb) {
    #pragma unroll
    for (int off = 32; off; off >>= 1) v += __shfl_down(v, off);
    int wave = threadIdx.x >> 6, lane = threadIdx.x & 63;
    if (lane == 0) sb[wave] = v;
    __syncthreads();
    float r = sb[0] + sb[1] + sb[2] + sb[3];
    __syncthreads();
    return r;
}

__device__ __forceinline__ float bmax(float v, float* sb) {
    #pragma unroll
    for (int off = 32; off; off >>= 1) v = fmaxf(v, __shfl_down(v, off));
    int wave = threadIdx.x >> 6, lane = threadIdx.x & 63;
    if (lane == 0) sb[wave] = v;
    __syncthreads();
    float r = fmaxf(fmaxf(sb[0], sb[1]), fmaxf(sb[2], sb[3]));
    __syncthreads();
    return r;
}

// ---------- init: hidden = x, acc(bf16) = 0, cum = 0 ----------
__global__ __launch_bounds__(256)
void init_kernel(const float* __restrict__ x, float* __restrict__ hidden,
                 bfu* __restrict__ acc, float* __restrict__ cum) {
    size_t i = (size_t)blockIdx.x * 256 + threadIdx.x;   // quad index over Rn*Dn/4
    float4 v = ((const float4*)x)[i];
    ((float4*)hidden)[i] = v;
    ushort4 z = {0, 0, 0, 0};
    *(ushort4*)(acc + i * 4) = z;
    if (i < Rn) cum[i] = 0.f;
}

// ---------- weight convert+transpose: Wh[n][k] = f16(W[k][n]) ----------
__global__ __launch_bounds__(256)
void transpose_cvt_kernel(const float* __restrict__ W, f16* __restrict__ Wh,
                          int K, int N) {
    __shared__ float tile[32][33];
    int k0 = blockIdx.y * 32, n0 = blockIdx.x * 32;
    int t = threadIdx.x;
    int r = t >> 5, c = t & 31;    // r 0..7, c 0..31
    #pragma unroll
    for (int j = 0; j < 4; j++)
        tile[r + j * 8][c] = W[(size_t)(k0 + r + j * 8) * N + n0 + c];
    __syncthreads();
    #pragma unroll
    for (int j = 0; j < 4; j++) {
        float v = tile[c][r + j * 8];
        size_t idx = (size_t)(n0 + r + j * 8) * K + k0 + c;
        Wh[idx] = (f16)v;
    }
}

// ---------- per-row: LayerNorm(hidden) -> nh (f16) ; entropy(hidden) -> ent ----------
__global__ __launch_bounds__(256)
void ln_ent_kernel(const float* __restrict__ hidden,
                   const float* __restrict__ g1, const float* __restrict__ b1,
                   f16* __restrict__ nh, float* __restrict__ ent_out) {
    __shared__ float sb[4];
    int row = blockIdx.x;
    int t = threadIdx.x;
    const float* h = hidden + (size_t)row * Dn;
    float4 hv = ((const float4*)h)[t];
    float vals[4] = {hv.x, hv.y, hv.z, hv.w};
    float s = 0.f, s2 = 0.f, mx = -INFINITY;
    #pragma unroll
    for (int i = 0; i < 4; i++) { s += vals[i]; s2 += vals[i]*vals[i]; mx = fmaxf(mx, vals[i]); }
    s  = bsum(s,  sb);
    s2 = bsum(s2, sb);
    mx = bmax(mx, sb);
    float mean = s * (1.f / Dn);
    float var  = s2 * (1.f / Dn) - mean * mean;
    float rstd = rsqrtf(var + EPSc);
    float Z = 0.f, S = 0.f;
    #pragma unroll
    for (int i = 0; i < 4; i++) { float e = expf(vals[i] - mx); Z += e; S += e * vals[i]; }
    Z = bsum(Z, sb);
    S = bsum(S, sb);
    if (t == 0) {
        ent_out[row] = (mx + logf(Z) - S / Z) * (1.0f / logf((float)Dn));
    }
    float4 g = ((const float4*)g1)[t];
    float4 bb = ((const float4*)b1)[t];
    f16x4 oh;
    oh[0] = (f16)((vals[0] - mean) * rstd * g.x + bb.x);
    oh[1] = (f16)((vals[1] - mean) * rstd * g.y + bb.y);
    oh[2] = (f16)((vals[2] - mean) * rstd * g.z + bb.z);
    oh[3] = (f16)((vals[3] - mean) * rstd * g.w + bb.w);
    *(f16x4*)(nh + (size_t)row * Dn + t * 4) = oh;
}

// ---------- pure-f16 MFMA GEMM: C = epi(A @ Bt^T + bias) ----------
// 128x128 tile, BK=32, 256 threads = 4 waves (2x2), wave tile 64x64 (MF=NF=4).
// T3+T4 counted-vmcnt 2-buffer pipeline: raw s_barrier (NO vmcnt0 drain) +
// s_waitcnt vmcnt(G). Iter t: STAGE(t+1) issued (stays in flight across the
// whole K-step), waitv<G> completes only stage(t), bar1 -> COMPUTE(t) -> bar2
// (WAR: all waves' ds_reads of buf t done before next iter's STAGE overwrites).
// 32 KB LDS + launch_bounds(256,4) -> 4 resident blocks/CU (TLP covers the rest).
// XCD-aware bijective block swizzle (T1): per-z-plane nwg % 8 == 0.
// LDS column-slot XOR-swizzle at global source + ds_read (0 conflicts, verified).
// MODE 0: gelu -> f16 C0.
// MODE 1: split-K over blockIdx.z (z=4): z==0 -> C0(f32) = res + bias + v;
//         z>=1 -> part slice z-1 (f16) = v (reduced by add_kernel).
template<int MODE>
__global__ __launch_bounds__(256, 4)
void gemm_f16(const f16* __restrict__ A, const f16* __restrict__ Bt,
              const float* __restrict__ bias, const float* __restrict__ res,
              void* __restrict__ C0, f16* __restrict__ part,
              int N, int LD, int KLEN) {
    constexpr int MF = 4, NF = 4;     // 16x16 frags per wave (wave tile 64x64)
    constexpr int G  = 4;             // global_load_lds per wave per stage
    __shared__ __align__(16) f16 sA[2][128 * 32];
    __shared__ __align__(16) f16 sB[2][128 * 32];
    int tid = threadIdx.x;
    int wave = tid >> 6, lane = tid & 63;
    int wm = wave >> 1, wn = wave & 1;
    int quad = lane >> 4, l15 = lane & 15;

    // XCD-aware bijective swizzle over the (y,x) plane (nwg % 8 == 0)
    int nwg = gridDim.x * gridDim.y;
    int bid = blockIdx.y * gridDim.x + blockIdx.x;
    int swz = (bid & 7) * (nwg >> 3) + (bid >> 3);
    int bx = swz % gridDim.x, by = swz / gridDim.x;
    int m0 = by * 128, n0 = bx * 128;
    int kbase = blockIdx.z * KLEN;

    f32x4 acc[MF][NF];
    #pragma unroll
    for (int i = 0; i < MF; i++)
        #pragma unroll
        for (int j = 0; j < NF; j++)
            acc[i][j] = (f32x4){0.f, 0.f, 0.f, 0.f};

    // staged row = lane>>2 (16 rows/GLL); swizzled source column slot
    int swzcol = ((lane & 3) ^ ((lane >> 3) & 3)) * 8;
    size_t aoff = (size_t)(m0 + wave * 32 + (lane >> 2)) * LD + kbase + swzcol;
    size_t boff = (size_t)(n0 + wave * 32 + (lane >> 2)) * LD + kbase + swzcol;
    const f16* gA = A + aoff;
    const f16* gB = Bt + boff;
    const int lA = wave * 1024;            // this wave's 32-row staging region
    const int swzrd = (quad ^ ((l15 >> 1) & 3)) * 8;   // swizzled read slot

    #define GLL(g, l) __builtin_amdgcn_global_load_lds( \
        (const __attribute__((address_space(1))) void*)(g), \
        (__attribute__((address_space(3))) void*)(l), 16, 0, 0)

    #define STAGE(BUF, KT) do { \
        size_t _ko = (size_t)(KT) * 32; \
        _Pragma("unroll") \
        for (int i = 0; i < 2; i++) { \
            GLL(gA + _ko + (size_t)i * 16 * LD, &sA[BUF][lA + i * 512]); \
            GLL(gB + _ko + (size_t)i * 16 * LD, &sB[BUF][lA + i * 512]); \
        } \
    } while (0)

    #define COMPUTE(BUF) do { \
        f16x8 af[MF], bf[NF]; \
        _Pragma("unroll") \
        for (int mt = 0; mt < MF; mt++) \
            af[mt] = *(const f16x8*)&sA[BUF][(wm * 64 + mt * 16 + l15) * 32 + swzrd]; \
        _Pragma("unroll") \
        for (int nt = 0; nt < NF; nt++) \
            bf[nt] = *(const f16x8*)&sB[BUF][(wn * 64 + nt * 16 + l15) * 32 + swzrd]; \
        _Pragma("unroll") \
        for (int mt = 0; mt < MF; mt++) \
            _Pragma("unroll") \
            for (int nt = 0; nt < NF; nt++) \
                acc[mt][nt] = __builtin_amdgcn_mfma_f32_16x16x32_f16(af[mt], bf[nt], acc[mt][nt], 0, 0, 0); \
    } while (0)

    const int nk = KLEN / 32;         // 32 (K=1024 or slice)
    STAGE(0, 0);                      // G outstanding
    for (int t = 0; t < nk; ++t) {
        if (t + 1 < nk) {
            STAGE((t + 1) & 1, t + 1);   // 2G outstanding; flies across this K-step
            waitv<G>();                  // stage(t) landed; stage(t+1) in flight
        } else {
            waitv<0>();                  // final stage landed
        }
        block_bar();                  // bar1: buf t visible to all waves
        COMPUTE(t & 1);
        block_bar();                  // bar2: all waves done reading buf t
    }
    #undef STAGE
    #undef COMPUTE
    #undef GLL

    // epilogue: D col = lane&15 (n), row = quad*4 + reg (m)
    f16* pp = (MODE == 1 && blockIdx.z > 0)
              ? part + (size_t)(blockIdx.z - 1) * (size_t)gridDim.y * 128 * N : part;
    #pragma unroll
    for (int nt = 0; nt < NF; nt++) {
        int gcol = n0 + wn * 64 + nt * 16 + l15;
        float bv = (MODE == 0 || blockIdx.z == 0) ? bias[gcol] : 0.f;
        #pragma unroll
        for (int mt = 0; mt < MF; mt++) {
            int grow = m0 + wm * 64 + mt * 16 + quad * 4;
            #pragma unroll
            for (int r = 0; r < 4; r++) {
                size_t off = (size_t)(grow + r) * N + gcol;
                float v = acc[mt][nt][r] + bv;
                if (MODE == 0) {
                    v = 0.5f * v * (1.0f + erff(v * 0.70710678118654752f));
                    ((f16*)C0)[off] = (f16)v;
                } else {
                    if (blockIdx.z == 0) ((float*)C0)[off] = res[off] + v;
                    else                 pp[off] = (f16)v;
                }
            }
        }
    }
}

// ---------- add partials: h += p0 + p1 + p2 (f16 split-K slices) ----------
__global__ __launch_bounds__(256)
void add_kernel(float* __restrict__ h, const f16* __restrict__ p) {
    size_t i = (size_t)blockIdx.x * 256 + threadIdx.x;   // quad index
    float4 a = ((float4*)h)[i];
    f16x4 q0 = ((const f16x4*)p)[i];
    f16x4 q1 = ((const f16x4*)(p + (size_t)CHUNK * Dn))[i];
    f16x4 q2 = ((const f16x4*)(p + (size_t)2 * CHUNK * Dn))[i];
    a.x += (float)q0[0] + (float)q1[0] + (float)q2[0];
    a.y += (float)q0[1] + (float)q1[1] + (float)q2[1];
    a.z += (float)q0[2] + (float)q1[2] + (float)q2[2];
    a.w += (float)q0[3] + (float)q1[3] + (float)q2[3];
    ((float4*)h)[i] = a;
}

// ---------- scores[r,m] = h_new[r,:] @ W_comp[:,m] + b_comp[m] ----------
__global__ __launch_bounds__(256)
void scores_kernel(const float* __restrict__ h, const float* __restrict__ Wc,
                   const float* __restrict__ bc, float* __restrict__ scores) {
    int row = blockIdx.x;
    int t = threadIdx.x;
    float acc[Mn] = {};
    const float* hr = h + (size_t)row * Dn;
    for (int d = t; d < Dn; d += 256) {
        float hv = hr[d];
        const float* w = Wc + (size_t)d * Mn;
        #pragma unroll
        for (int m = 0; m < Mn; m++) acc[m] += hv * w[m];
    }
    __shared__ float red[Mn][4];
    int wave = t >> 6, lane = t & 63;
    #pragma unroll
    for (int m = 0; m < Mn; m++) {
        float v = acc[m];
        #pragma unroll
        for (int off = 32; off; off >>= 1) v += __shfl_down(v, off);
        if (lane == 0) red[m][wave] = v;
    }
    __syncthreads();
    if (t < Mn) {
        float v = red[t][0] + red[t][1] + red[t][2] + red[t][3];
        scores[(size_t)row * Mn + t] = v + bc[t];
    }
}

// ---------- softmax over L (axis=1) per (b,m) ----------
__global__ __launch_bounds__(256)
void softmaxL_kernel(const float* __restrict__ scores, float* __restrict__ wL) {
    __shared__ float sb[4];
    int b = blockIdx.x / Mn, m = blockIdx.x % Mn;
    int t = threadIdx.x;
    const float* s = scores + (size_t)b * Ln * Mn + m;
    float mx = -INFINITY;
    for (int l = t; l < Ln; l += 256) mx = fmaxf(mx, s[(size_t)l * Mn]);
    mx = bmax(mx, sb);
    float z = 0.f;
    for (int l = t; l < Ln; l += 256) z += expf(s[(size_t)l * Mn] - mx);
    z = bsum(z, sb);
    float inv = 1.0f / z;
    float* w = wL + (size_t)b * Ln * Mn + m;
    for (int l = t; l < Ln; l += 256) w[(size_t)l * Mn] = expf(s[(size_t)l * Mn] - mx) * inv;
}

// ---------- memory partials: mpart[lc][b][m][d] = sum_{l in chunk lc} wL[b,l,m]*h[b,l,d] ----------
__global__ __launch_bounds__(256)
void memory_kernel(const float* __restrict__ h, const float* __restrict__ wL,
                   float* __restrict__ mpart) {
    int bid = blockIdx.x;                 // Bn * (Dn/256) * LCH = 512 blocks
    int lc = bid & (LCH - 1);
    int dc = (bid >> 5) & 3;
    int b  = bid >> 7;
    int t = threadIdx.x;
    int d = dc * 256 + t;
    int l0 = lc * LSUB;
    float acc[Mn] = {};
    const float* hp = h + ((size_t)b * Ln + l0) * Dn + d;
    const float* wp = wL + ((size_t)b * Ln + l0) * Mn;
    for (int l = 0; l < LSUB; l++) {
        float hv = hp[(size_t)l * Dn];
        float4 w0 = *(const float4*)(wp + (size_t)l * Mn);
        float4 w1 = *(const float4*)(wp + (size_t)l * Mn + 4);
        acc[0] += w0.x * hv; acc[1] += w0.y * hv; acc[2] += w0.z * hv; acc[3] += w0.w * hv;
        acc[4] += w1.x * hv; acc[5] += w1.y * hv; acc[6] += w1.z * hv; acc[7] += w1.w * hv;
    }
    #pragma unroll
    for (int m = 0; m < Mn; m++)
        mpart[(((size_t)lc * Bn + b) * Mn + m) * Dn + d] = acc[m];
}

// ---------- reduce partials: mem[b][m][d] = sum_lc mpart[lc][b][m][d] ----------
__global__ __launch_bounds__(256)
void memreduce_kernel(const float* __restrict__ mpart, float* __restrict__ mem) {
    int i = blockIdx.x * 256 + threadIdx.x;   // over Bn*Mn*Dn = 32768
    float s = 0.f;
    #pragma unroll
    for (int lc = 0; lc < LCH; lc++) s += mpart[(size_t)lc * Bn * Mn * Dn + i];
    mem[i] = s;
}

// ---------- memW[b,m,d] = sum_k mem[b,m,k] * W_attn[k,d]  (tiny f32 GEMM, 32x1024x1024) ----------
__global__ __launch_bounds__(256)
void memw_kernel(const float* __restrict__ mem, const float* __restrict__ W,
                 float* __restrict__ memW) {
    __shared__ float sm[Dn];
    int bm = blockIdx.x >> 2;             // 0..31 (b*Mn+m)
    int dc = (blockIdx.x & 3) * 256;
    int t = threadIdx.x;
    const float* mrow = mem + (size_t)bm * Dn;
    for (int k = t; k < Dn; k += 256) sm[k] = mrow[k];
    __syncthreads();
    int d = dc + t;
    float a = 0.f;
    for (int k = 0; k < Dn; k++)
        a += sm[k] * W[(size_t)k * Dn + d];
    memW[(size_t)bm * Dn + d] = a;
}

// ---------- fused ctx + entropy gate + ACT halting ----------
__global__ __launch_bounds__(256)
void ctx_gate_kernel(const float* __restrict__ scores, const float* __restrict__ memW,
                     const float* __restrict__ battn, const float* __restrict__ hnew,
                     float* __restrict__ hidden, const float* __restrict__ ent,
                     const float* __restrict__ Wh, const float* __restrict__ bh,
                     bfu* __restrict__ acc, float* __restrict__ cum) {
    __shared__ float sb[4];
    int row = blockIdx.x;                 // 0..Rn-1
    int b = row >> 12;                    // row / Ln (Ln = 4096)
    int t = threadIdx.x;
    bool upd = ent[row] > THRc;
    float4 hv;
    if (upd) {
        const float* s = scores + (size_t)row * Mn;
        float sv[Mn];
        float mx = -INFINITY;
        #pragma unroll
        for (int m = 0; m < Mn; m++) { sv[m] = s[m]; mx = fmaxf(mx, sv[m]); }
        float z = 0.f;
        #pragma unroll
        for (int m = 0; m < Mn; m++) { sv[m] = expf(sv[m] - mx); z += sv[m]; }
        float inv = 1.0f / z;
        float4 bv = ((const float4*)battn)[t];
        float a0 = bv.x, a1 = bv.y, a2 = bv.z, a3 = bv.w;
        #pragma unroll
        for (int m = 0; m < Mn; m++) {
            float w = sv[m] * inv;
            float4 mw = ((const float4*)(memW + ((size_t)b * Mn + m) * Dn))[t];
            a0 += w * mw.x; a1 += w * mw.y; a2 += w * mw.z; a3 += w * mw.w;
        }
        hv = ((const float4*)(hnew + (size_t)row * Dn))[t];
        hv.x += a0; hv.y += a1; hv.z += a2; hv.w += a3;
    } else {
        hv = ((const float4*)(hidden + (size_t)row * Dn))[t];
    }
    float4 wv = ((const float4*)Wh)[t];
    float dot = hv.x*wv.x + hv.y*wv.y + hv.z*wv.z + hv.w*wv.w;
    dot = bsum(dot, sb);
    float p = 1.0f / (1.0f + expf(-(dot + bh[0])));
    float c = cum[row];
    float w = p * (1.0f - c);
    ushort4 a = *(ushort4*)(acc + (size_t)row * Dn + t * 4);
    ushort4 o;
    o.x = f2b(b2f(a.x) + w * hv.x);
    o.y = f2b(b2f(a.y) + w * hv.y);
    o.z = f2b(b2f(a.z) + w * hv.z);
    o.w = f2b(b2f(a.w) + w * hv.w);
    *(ushort4*)(acc + (size_t)row * Dn + t * 4) = o;
    ((float4*)(hidden + (size_t)row * Dn))[t] = hv;
    __syncthreads();                 // all waves read cum[row] before lane0 overwrites it
    if (t == 0) cum[row] = c + w;
}

// ---------- final: out = LN(acc + (1-cum)*hidden, g2, b2) ----------
__global__ __launch_bounds__(256)
void final_ln_kernel(const bfu* __restrict__ acc, const float* __restrict__ cum,
                     const float* __restrict__ hidden,
                     const float* __restrict__ g2, const float* __restrict__ b2,
                     float* __restrict__ out) {
    __shared__ float sb[4];
    int row = blockIdx.x;
    int t = threadIdx.x;
    float c = 1.0f - cum[row];
    ushort4 a = *(const ushort4*)(acc + (size_t)row * Dn + t * 4);
    float4 h = ((const float4*)(hidden + (size_t)row * Dn))[t];
    float vals[4];
    vals[0] = b2f(a.x) + c * h.x; vals[1] = b2f(a.y) + c * h.y;
    vals[2] = b2f(a.z) + c * h.z; vals[3] = b2f(a.w) + c * h.w;
    float s = 0.f, s2 = 0.f;
    #pragma unroll
    for (int i = 0; i < 4; i++) { s += vals[i]; s2 += vals[i]*vals[i]; }
    s  = bsum(s,  sb);
    s2 = bsum(s2, sb);
    float mean = s * (1.f / Dn);
    float var  = s2 * (1.f / Dn) - mean * mean;
    float rstd = rsqrtf(var + EPSc);
    float4 g = ((const float4*)g2)[t];
    float4 bb = ((const float4*)b2)[t];
    float4 o;
    o.x = (vals[0] - mean) * rstd * g.x + bb.x;
    o.y = (vals[1] - mean) * rstd * g.y + bb.y;
    o.z = (vals[2] - mean) * rstd * g.z + bb.z;
    o.w = (vals[3] - mean) * rstd * g.w + bb.w;
    ((float4*)(out + (size_t)row * Dn))[t] = o;
}

extern "C" void kernel_launch(void* const* d_in, const int* in_sizes, int n_in,
                              void* d_out, int out_size, void* d_ws, size_t ws_size,
                              hipStream_t stream) {
    (void)in_sizes; (void)n_in; (void)out_size; (void)ws_size;
    const float* x      = (const float*)d_in[0];
    const float* g1     = (const float*)d_in[1];
    const float* b1     = (const float*)d_in[2];
    const float* W_up   = (const float*)d_in[3];
    const float* b_up   = (const float*)d_in[4];
    const float* W_down = (const float*)d_in[5];
    const float* b_down = (const float*)d_in[6];
    const float* W_halt = (const float*)d_in[7];
    const float* b_halt = (const float*)d_in[8];
    const float* W_comp = (const float*)d_in[9];
    const float* b_comp = (const float*)d_in[10];
    const float* W_attn = (const float*)d_in[11];
    const float* b_attn = (const float*)d_in[12];
    const float* g2     = (const float*)d_in[13];
    const float* b2     = (const float*)d_in[14];
    float* out = (float*)d_out;

    // ws layout — ~257 MB total (< 264.5 MB known-clean)
    char* wsb = (char*)d_ws;
    size_t off = 0;
    float* hidden = (float*)(wsb + off); off += (size_t)Rn * Dn * 4;      // 67.1 MB
    float* hnew   = (float*)(wsb + off); off += (size_t)Rn * Dn * 4;      // 67.1 MB
    bfu*   accb   = (bfu*)  (wsb + off); off += (size_t)Rn * Dn * 2;      // 33.6 MB (bf16)
    f16*   nh     = (f16*)  (wsb + off); off += (size_t)CHUNK * Dn * 2;   //  8.4 MB
    f16*   uh     = (f16*)  (wsb + off); off += (size_t)CHUNK * DIn * 2;  // 33.6 MB
    f16*   pf     = (f16*)  (wsb + off); off += (size_t)3 * CHUNK * Dn * 2; // 25.2 MB (3 f16 split-K partials)
    f16*   WupTh  = (f16*)  (wsb + off); off += (size_t)DIn * Dn * 2;     //  8.4 MB
    f16*   WdnTh  = (f16*)  (wsb + off); off += (size_t)Dn * DIn * 2;     //  8.4 MB
    float* scores = (float*)(wsb + off); off += (size_t)Rn * Mn * 4;      //  0.5 MB
    float* wL     = (float*)(wsb + off); off += (size_t)Rn * Mn * 4;      //  0.5 MB
    float* mpart  = (float*)(wsb + off); off += (size_t)LCH * Bn * Mn * Dn * 4;  // 4.2 MB
    float* memb   = (float*)(wsb + off); off += (size_t)Bn * Mn * Dn * 4; //  0.13 MB
    float* memW   = (float*)(wsb + off); off += (size_t)Bn * Mn * Dn * 4; //  0.13 MB
    float* ent    = (float*)(wsb + off); off += (size_t)Rn * 4;
    float* cum    = (float*)(wsb + off); off += (size_t)Rn * 4;

    transpose_cvt_kernel<<<dim3(DIn / 32, Dn / 32), 256, 0, stream>>>(W_up,   WupTh, Dn, DIn);
    transpose_cvt_kernel<<<dim3(Dn / 32, DIn / 32), 256, 0, stream>>>(W_down, WdnTh, DIn, Dn);

    init_kernel<<<(Rn * Dn / 4) / 256, 256, 0, stream>>>(x, hidden, accb, cum);

    for (int s = 0; s < NSTEP; ++s) {
        for (int c = 0; c < NCH; ++c) {
            ln_ent_kernel<<<CHUNK, 256, 0, stream>>>(
                hidden + (size_t)c * CHUNK * Dn, g1, b1, nh, ent + (size_t)c * CHUNK);
            // up: M=4096, N=4096, K=1024; 1024 blocks, 4 resident/CU
            gemm_f16<0><<<dim3(DIn / 128, CHUNK / 128, 1), 256, 0, stream>>>(
                nh, WupTh, b_up, nullptr, uh, nullptr, DIn, Dn, Dn);
            // down: M=4096, N=1024, K=4096 split z=4; 1024 blocks, 4 resident/CU
            gemm_f16<1><<<dim3(Dn / 128, CHUNK / 128, 4), 256, 0, stream>>>(
                uh, WdnTh, b_down, hidden + (size_t)c * CHUNK * Dn,
                hnew + (size_t)c * CHUNK * Dn, pf, Dn, DIn, DIn / 4);
            add_kernel<<<(CHUNK * Dn / 4) / 256, 256, 0, stream>>>(
                hnew + (size_t)c * CHUNK * Dn, pf);
        }
        scores_kernel<<<Rn, 256, 0, stream>>>(hnew, W_comp, b_comp, scores);
        softmaxL_kernel<<<Bn * Mn, 256, 0, stream>>>(scores, wL);
        memory_kernel<<<Bn * (Dn / 256) * LCH, 256, 0, stream>>>(hnew, wL, mpart);
        memreduce_kernel<<<(Bn * Mn * Dn) / 256, 256, 0, stream>>>(mpart, memb);
        memw_kernel<<<Bn * Mn * 4, 256, 0, stream>>>(memb, W_attn, memW);
        ctx_gate_kernel<<<Rn, 256, 0, stream>>>(scores, memW, b_attn, hnew, hidden,
                                                ent, W_halt, b_halt, accb, cum);
    }

    final_ln_kernel<<<Rn, 256, 0, stream>>>(accb, cum, hidden, g2, b2, out);
}

// Round 8
// 2797.740 us; speedup vs baseline: 1.0586x; 1.0586x over previous
//
#include <hip/hip_runtime.h>
#include <math.h>

#define Bn 4
#define Ln 4096
#define Dn 1024
#define DIn 4096
#define Mn 8
#define Rn (Bn*Ln)          // 16384 rows
#define CHUNK 4096
#define NCH (Rn/CHUNK)      // 4 chunks
#define NSTEP 4
#define THRc 0.5f
#define EPSc 1e-6f
#define LCH 32              // L-chunks for memory partials
#define LSUB (Ln/LCH)       // 128

typedef unsigned short bfu;
typedef _Float16 f16;
typedef __attribute__((ext_vector_type(8))) _Float16 f16x8;  // MFMA A/B frag (4 VGPRs)
typedef __attribute__((ext_vector_type(4))) _Float16 f16x4;
typedef __attribute__((ext_vector_type(4))) float f32x4;     // MFMA C/D frag

// ---------- helpers ----------
__device__ __forceinline__ bfu f2b(float f) {
    union { float f; unsigned i; } v; v.f = f;
    unsigned r = v.i + 0x7FFFu + ((v.i >> 16) & 1u);  // RNE
    return (bfu)(r >> 16);
}
__device__ __forceinline__ float b2f(bfu u) {
    union { float f; unsigned i; } v; v.i = ((unsigned)u) << 16; return v.f;
}
// tanh-form gelu: v*sigmoid(2u), u = sqrt(2/pi)*(v + 0.044715 v^3).
// |gelu_tanh - gelu_erf| < ~1e-3 << 0.03125 tolerance; ~10 VALU instrs vs ~30 for erff.
__device__ __forceinline__ float gelu_f(float v) {
    float u = v * (0.7978845608028654f + 0.0356774081366315f * v * v);
    return v / (1.0f + __expf(-2.0f * u));
}

// ---------- block-wide reductions (block = 256 = 4 waves) ----------
__device__ __forceinline__ float bsum(float v, float* sb) {
    #pragma unroll
    for (int off = 32; off; off >>= 1) v += __shfl_down(v, off);
    int wave = threadIdx.x >> 6, lane = threadIdx.x & 63;
    if (lane == 0) sb[wave] = v;
    __syncthreads();
    float r = sb[0] + sb[1] + sb[2] + sb[3];
    __syncthreads();
    return r;
}

__device__ __forceinline__ float bmax(float v, float* sb) {
    #pragma unroll
    for (int off = 32; off; off >>= 1) v = fmaxf(v, __shfl_down(v, off));
    int wave = threadIdx.x >> 6, lane = threadIdx.x & 63;
    if (lane == 0) sb[wave] = v;
    __syncthreads();
    float r = fmaxf(fmaxf(sb[0], sb[1]), fmaxf(sb[2], sb[3]));
    __syncthreads();
    return r;
}

// ---------- init: hidden = x, acc(bf16) = 0, cum = 0 ----------
__global__ __launch_bounds__(256)
void init_kernel(const float* __restrict__ x, float* __restrict__ hidden,
                 bfu* __restrict__ acc, float* __restrict__ cum) {
    size_t i = (size_t)blockIdx.x * 256 + threadIdx.x;   // quad index over Rn*Dn/4
    float4 v = ((const float4*)x)[i];
    ((float4*)hidden)[i] = v;
    ushort4 z = {0, 0, 0, 0};
    *(ushort4*)(acc + i * 4) = z;
    if (i < Rn) cum[i] = 0.f;
}

// ---------- weight convert+transpose: Wh[n][k] = f16(W[k][n]) ----------
__global__ __launch_bounds__(256)
void transpose_cvt_kernel(const float* __restrict__ W, f16* __restrict__ Wh,
                          int K, int N) {
    __shared__ float tile[32][33];
    int k0 = blockIdx.y * 32, n0 = blockIdx.x * 32;
    int t = threadIdx.x;
    int r = t >> 5, c = t & 31;    // r 0..7, c 0..31
    #pragma unroll
    for (int j = 0; j < 4; j++)
        tile[r + j * 8][c] = W[(size_t)(k0 + r + j * 8) * N + n0 + c];
    __syncthreads();
    #pragma unroll
    for (int j = 0; j < 4; j++) {
        float v = tile[c][r + j * 8];
        size_t idx = (size_t)(n0 + r + j * 8) * K + k0 + c;
        Wh[idx] = (f16)v;
    }
}

// ---------- per-row: LayerNorm(hidden) -> nh (f16) ; entropy(hidden) -> ent ----------
__global__ __launch_bounds__(256)
void ln_ent_kernel(const float* __restrict__ hidden,
                   const float* __restrict__ g1, const float* __restrict__ b1,
                   f16* __restrict__ nh, float* __restrict__ ent_out) {
    __shared__ float sb[4];
    int row = blockIdx.x;
    int t = threadIdx.x;
    const float* h = hidden + (size_t)row * Dn;
    float4 hv = ((const float4*)h)[t];
    float vals[4] = {hv.x, hv.y, hv.z, hv.w};
    float s = 0.f, s2 = 0.f, mx = -INFINITY;
    #pragma unroll
    for (int i = 0; i < 4; i++) { s += vals[i]; s2 += vals[i]*vals[i]; mx = fmaxf(mx, vals[i]); }
    s  = bsum(s,  sb);
    s2 = bsum(s2, sb);
    mx = bmax(mx, sb);
    float mean = s * (1.f / Dn);
    float var  = s2 * (1.f / Dn) - mean * mean;
    float rstd = rsqrtf(var + EPSc);
    float Z = 0.f, S = 0.f;
    #pragma unroll
    for (int i = 0; i < 4; i++) { float e = expf(vals[i] - mx); Z += e; S += e * vals[i]; }
    Z = bsum(Z, sb);
    S = bsum(S, sb);
    if (t == 0) {
        ent_out[row] = (mx + logf(Z) - S / Z) * (1.0f / logf((float)Dn));
    }
    float4 g = ((const float4*)g1)[t];
    float4 bb = ((const float4*)b1)[t];
    f16x4 oh;
    oh[0] = (f16)((vals[0] - mean) * rstd * g.x + bb.x);
    oh[1] = (f16)((vals[1] - mean) * rstd * g.y + bb.y);
    oh[2] = (f16)((vals[2] - mean) * rstd * g.z + bb.z);
    oh[3] = (f16)((vals[3] - mean) * rstd * g.w + bb.w);
    *(f16x4*)(nh + (size_t)row * Dn + t * 4) = oh;
}

// ---------- pure-f16 MFMA GEMM: C = epi(A @ Bt^T + bias) ----------
// 128x128 tile, BK=32, 256 threads = 4 waves (2x2), wave tile 64x64 (MF=NF=4).
// 2-PHASE pipeline (round-6 proven-best at occupancy): 2 LDS buffers (32 KB),
// one __syncthreads per K-step, STAGE(t+1) issued BEFORE COMPUTE(t). Latency
// hiding via TLP: launch_bounds(256,4) + 32 KB LDS -> 4 resident blocks/CU.
// (r7 A/B: counted-vmcnt + 2 raw barriers is WORSE here — only pays at low
// occupancy or in 8-phase schedules.)
// XCD-aware bijective block swizzle (T1); LDS XOR-swizzle (0 conflicts, verified).
// MODE 0: gelu -> f16 C0.
// MODE 1: split-K over blockIdx.z (z=4): z==0 -> C0(f32) = res + bias + v;
//         z>=1 -> part slice z-1 (f16) = v (reduced by add_kernel).
template<int MODE>
__global__ __launch_bounds__(256, 4)
void gemm_f16(const f16* __restrict__ A, const f16* __restrict__ Bt,
              const float* __restrict__ bias, const float* __restrict__ res,
              void* __restrict__ C0, f16* __restrict__ part,
              int N, int LD, int KLEN) {
    constexpr int MF = 4, NF = 4;     // 16x16 frags per wave (wave tile 64x64)
    __shared__ __align__(16) f16 sA[2][128 * 32];
    __shared__ __align__(16) f16 sB[2][128 * 32];
    int tid = threadIdx.x;
    int wave = tid >> 6, lane = tid & 63;
    int wm = wave >> 1, wn = wave & 1;
    int quad = lane >> 4, l15 = lane & 15;

    // XCD-aware bijective swizzle over the (y,x) plane (nwg % 8 == 0)
    int nwg = gridDim.x * gridDim.y;
    int bid = blockIdx.y * gridDim.x + blockIdx.x;
    int swz = (bid & 7) * (nwg >> 3) + (bid >> 3);
    int bx = swz % gridDim.x, by = swz / gridDim.x;
    int m0 = by * 128, n0 = bx * 128;
    int kbase = blockIdx.z * KLEN;

    f32x4 acc[MF][NF];
    #pragma unroll
    for (int i = 0; i < MF; i++)
        #pragma unroll
        for (int j = 0; j < NF; j++)
            acc[i][j] = (f32x4){0.f, 0.f, 0.f, 0.f};

    // staged row = lane>>2 (16 rows/GLL); swizzled source column slot
    int swzcol = ((lane & 3) ^ ((lane >> 3) & 3)) * 8;
    size_t aoff = (size_t)(m0 + wave * 32 + (lane >> 2)) * LD + kbase + swzcol;
    size_t boff = (size_t)(n0 + wave * 32 + (lane >> 2)) * LD + kbase + swzcol;
    const f16* gA = A + aoff;
    const f16* gB = Bt + boff;
    const int lA = wave * 1024;            // this wave's 32-row staging region
    const int swzrd = (quad ^ ((l15 >> 1) & 3)) * 8;   // swizzled read slot

    #define GLL(g, l) __builtin_amdgcn_global_load_lds( \
        (const __attribute__((address_space(1))) void*)(g), \
        (__attribute__((address_space(3))) void*)(l), 16, 0, 0)

    #define STAGE(BUF, KT) do { \
        size_t _ko = (size_t)(KT) * 32; \
        _Pragma("unroll") \
        for (int i = 0; i < 2; i++) { \
            GLL(gA + _ko + (size_t)i * 16 * LD, &sA[BUF][lA + i * 512]); \
            GLL(gB + _ko + (size_t)i * 16 * LD, &sB[BUF][lA + i * 512]); \
        } \
    } while (0)

    #define COMPUTE(BUF) do { \
        f16x8 af[MF], bf[NF]; \
        _Pragma("unroll") \
        for (int mt = 0; mt < MF; mt++) \
            af[mt] = *(const f16x8*)&sA[BUF][(wm * 64 + mt * 16 + l15) * 32 + swzrd]; \
        _Pragma("unroll") \
        for (int nt = 0; nt < NF; nt++) \
            bf[nt] = *(const f16x8*)&sB[BUF][(wn * 64 + nt * 16 + l15) * 32 + swzrd]; \
        _Pragma("unroll") \
        for (int mt = 0; mt < MF; mt++) \
            _Pragma("unroll") \
            for (int nt = 0; nt < NF; nt++) \
                acc[mt][nt] = __builtin_amdgcn_mfma_f32_16x16x32_f16(af[mt], bf[nt], acc[mt][nt], 0, 0, 0); \
    } while (0)

    const int nk = KLEN / 32;         // 32 (K=1024 or slice)
    STAGE(0, 0);
    __syncthreads();                  // buf0 landed for all waves
    int t = 0;
    for (; t < nk - 1; ++t) {
        STAGE((t + 1) & 1, t + 1);    // next tile's loads fly under the MFMAs
        COMPUTE(t & 1);
        __syncthreads();              // drain: buf t+1 ready; buf t reads done
    }
    COMPUTE(t & 1);
    #undef STAGE
    #undef COMPUTE
    #undef GLL

    // epilogue: D col = lane&15 (n), row = quad*4 + reg (m)
    f16* pp = (MODE == 1 && blockIdx.z > 0)
              ? part + (size_t)(blockIdx.z - 1) * (size_t)gridDim.y * 128 * N : part;
    #pragma unroll
    for (int nt = 0; nt < NF; nt++) {
        int gcol = n0 + wn * 64 + nt * 16 + l15;
        float bv = (MODE == 0 || blockIdx.z == 0) ? bias[gcol] : 0.f;
        #pragma unroll
        for (int mt = 0; mt < MF; mt++) {
            int grow = m0 + wm * 64 + mt * 16 + quad * 4;
            #pragma unroll
            for (int r = 0; r < 4; r++) {
                size_t off = (size_t)(grow + r) * N + gcol;
                float v = acc[mt][nt][r] + bv;
                if (MODE == 0) {
                    ((f16*)C0)[off] = (f16)gelu_f(v);
                } else {
                    if (blockIdx.z == 0) ((float*)C0)[off] = res[off] + v;
                    else                 pp[off] = (f16)v;
                }
            }
        }
    }
}

// ---------- add partials: h += p0 + p1 + p2 (f16 split-K slices) ----------
__global__ __launch_bounds__(256)
void add_kernel(float* __restrict__ h, const f16* __restrict__ p) {
    size_t i = (size_t)blockIdx.x * 256 + threadIdx.x;   // quad index
    float4 a = ((float4*)h)[i];
    f16x4 q0 = ((const f16x4*)p)[i];
    f16x4 q1 = ((const f16x4*)(p + (size_t)CHUNK * Dn))[i];
    f16x4 q2 = ((const f16x4*)(p + (size_t)2 * CHUNK * Dn))[i];
    a.x += (float)q0[0] + (float)q1[0] + (float)q2[0];
    a.y += (float)q0[1] + (float)q1[1] + (float)q2[1];
    a.z += (float)q0[2] + (float)q1[2] + (float)q2[2];
    a.w += (float)q0[3] + (float)q1[3] + (float)q2[3];
    ((float4*)h)[i] = a;
}

// ---------- scores[r,m] = h_new[r,:] @ W_comp[:,m] + b_comp[m] ----------
__global__ __launch_bounds__(256)
void scores_kernel(const float* __restrict__ h, const float* __restrict__ Wc,
                   const float* __restrict__ bc, float* __restrict__ scores) {
    int row = blockIdx.x;
    int t = threadIdx.x;
    float acc[Mn] = {};
    const float* hr = h + (size_t)row * Dn;
    for (int d = t; d < Dn; d += 256) {
        float hv = hr[d];
        const float* w = Wc + (size_t)d * Mn;
        #pragma unroll
        for (int m = 0; m < Mn; m++) acc[m] += hv * w[m];
    }
    __shared__ float red[Mn][4];
    int wave = t >> 6, lane = t & 63;
    #pragma unroll
    for (int m = 0; m < Mn; m++) {
        float v = acc[m];
        #pragma unroll
        for (int off = 32; off; off >>= 1) v += __shfl_down(v, off);
        if (lane == 0) red[m][wave] = v;
    }
    __syncthreads();
    if (t < Mn) {
        float v = red[t][0] + red[t][1] + red[t][2] + red[t][3];
        scores[(size_t)row * Mn + t] = v + bc[t];
    }
}

// ---------- softmax over L (axis=1) per (b,m) ----------
__global__ __launch_bounds__(256)
void softmaxL_kernel(const float* __restrict__ scores, float* __restrict__ wL) {
    __shared__ float sb[4];
    int b = blockIdx.x / Mn, m = blockIdx.x % Mn;
    int t = threadIdx.x;
    const float* s = scores + (size_t)b * Ln * Mn + m;
    float mx = -INFINITY;
    for (int l = t; l < Ln; l += 256) mx = fmaxf(mx, s[(size_t)l * Mn]);
    mx = bmax(mx, sb);
    float z = 0.f;
    for (int l = t; l < Ln; l += 256) z += expf(s[(size_t)l * Mn] - mx);
    z = bsum(z, sb);
    float inv = 1.0f / z;
    float* w = wL + (size_t)b * Ln * Mn + m;
    for (int l = t; l < Ln; l += 256) w[(size_t)l * Mn] = expf(s[(size_t)l * Mn] - mx) * inv;
}

// ---------- memory partials: mpart[lc][b][m][d] = sum_{l in chunk lc} wL[b,l,m]*h[b,l,d] ----------
__global__ __launch_bounds__(256)
void memory_kernel(const float* __restrict__ h, const float* __restrict__ wL,
                   float* __restrict__ mpart) {
    int bid = blockIdx.x;                 // Bn * (Dn/256) * LCH = 512 blocks
    int lc = bid & (LCH - 1);
    int dc = (bid >> 5) & 3;
    int b  = bid >> 7;
    int t = threadIdx.x;
    int d = dc * 256 + t;
    int l0 = lc * LSUB;
    float acc[Mn] = {};
    const float* hp = h + ((size_t)b * Ln + l0) * Dn + d;
    const float* wp = wL + ((size_t)b * Ln + l0) * Mn;
    for (int l = 0; l < LSUB; l++) {
        float hv = hp[(size_t)l * Dn];
        float4 w0 = *(const float4*)(wp + (size_t)l * Mn);
        float4 w1 = *(const float4*)(wp + (size_t)l * Mn + 4);
        acc[0] += w0.x * hv; acc[1] += w0.y * hv; acc[2] += w0.z * hv; acc[3] += w0.w * hv;
        acc[4] += w1.x * hv; acc[5] += w1.y * hv; acc[6] += w1.z * hv; acc[7] += w1.w * hv;
    }
    #pragma unroll
    for (int m = 0; m < Mn; m++)
        mpart[(((size_t)lc * Bn + b) * Mn + m) * Dn + d] = acc[m];
}

// ---------- reduce partials: mem[b][m][d] = sum_lc mpart[lc][b][m][d] ----------
__global__ __launch_bounds__(256)
void memreduce_kernel(const float* __restrict__ mpart, float* __restrict__ mem) {
    int i = blockIdx.x * 256 + threadIdx.x;   // over Bn*Mn*Dn = 32768
    float s = 0.f;
    #pragma unroll
    for (int lc = 0; lc < LCH; lc++) s += mpart[(size_t)lc * Bn * Mn * Dn + i];
    mem[i] = s;
}

// ---------- memW[b,m,d] = sum_k mem[b,m,k] * W_attn[k,d]  (tiny f32 GEMM, 32x1024x1024) ----------
__global__ __launch_bounds__(256)
void memw_kernel(const float* __restrict__ mem, const float* __restrict__ W,
                 float* __restrict__ memW) {
    __shared__ float sm[Dn];
    int bm = blockIdx.x >> 2;             // 0..31 (b*Mn+m)
    int dc = (blockIdx.x & 3) * 256;
    int t = threadIdx.x;
    const float* mrow = mem + (size_t)bm * Dn;
    for (int k = t; k < Dn; k += 256) sm[k] = mrow[k];
    __syncthreads();
    int d = dc + t;
    float a = 0.f;
    for (int k = 0; k < Dn; k++)
        a += sm[k] * W[(size_t)k * Dn + d];
    memW[(size_t)bm * Dn + d] = a;
}

// ---------- fused ctx + entropy gate + ACT halting ----------
__global__ __launch_bounds__(256)
void ctx_gate_kernel(const float* __restrict__ scores, const float* __restrict__ memW,
                     const float* __restrict__ battn, const float* __restrict__ hnew,
                     float* __restrict__ hidden, const float* __restrict__ ent,
                     const float* __restrict__ Wh, const float* __restrict__ bh,
                     bfu* __restrict__ acc, float* __restrict__ cum) {
    __shared__ float sb[4];
    int row = blockIdx.x;                 // 0..Rn-1
    int b = row >> 12;                    // row / Ln (Ln = 4096)
    int t = threadIdx.x;
    bool upd = ent[row] > THRc;
    float4 hv;
    if (upd) {
        const float* s = scores + (size_t)row * Mn;
        float sv[Mn];
        float mx = -INFINITY;
        #pragma unroll
        for (int m = 0; m < Mn; m++) { sv[m] = s[m]; mx = fmaxf(mx, sv[m]); }
        float z = 0.f;
        #pragma unroll
        for (int m = 0; m < Mn; m++) { sv[m] = expf(sv[m] - mx); z += sv[m]; }
        float inv = 1.0f / z;
        float4 bv = ((const float4*)battn)[t];
        float a0 = bv.x, a1 = bv.y, a2 = bv.z, a3 = bv.w;
        #pragma unroll
        for (int m = 0; m < Mn; m++) {
            float w = sv[m] * inv;
            float4 mw = ((const float4*)(memW + ((size_t)b * Mn + m) * Dn))[t];
            a0 += w * mw.x; a1 += w * mw.y; a2 += w * mw.z; a3 += w * mw.w;
        }
        hv = ((const float4*)(hnew + (size_t)row * Dn))[t];
        hv.x += a0; hv.y += a1; hv.z += a2; hv.w += a3;
    } else {
        hv = ((const float4*)(hidden + (size_t)row * Dn))[t];
    }
    float4 wv = ((const float4*)Wh)[t];
    float dot = hv.x*wv.x + hv.y*wv.y + hv.z*wv.z + hv.w*wv.w;
    dot = bsum(dot, sb);
    float p = 1.0f / (1.0f + expf(-(dot + bh[0])));
    float c = cum[row];
    float w = p * (1.0f - c);
    ushort4 a = *(ushort4*)(acc + (size_t)row * Dn + t * 4);
    ushort4 o;
    o.x = f2b(b2f(a.x) + w * hv.x);
    o.y = f2b(b2f(a.y) + w * hv.y);
    o.z = f2b(b2f(a.z) + w * hv.z);
    o.w = f2b(b2f(a.w) + w * hv.w);
    *(ushort4*)(acc + (size_t)row * Dn + t * 4) = o;
    ((float4*)(hidden + (size_t)row * Dn))[t] = hv;
    __syncthreads();                 // all waves read cum[row] before lane0 overwrites it
    if (t == 0) cum[row] = c + w;
}

// ---------- final: out = LN(acc + (1-cum)*hidden, g2, b2) ----------
__global__ __launch_bounds__(256)
void final_ln_kernel(const bfu* __restrict__ acc, const float* __restrict__ cum,
                     const float* __restrict__ hidden,
                     const float* __restrict__ g2, const float* __restrict__ b2,
                     float* __restrict__ out) {
    __shared__ float sb[4];
    int row = blockIdx.x;
    int t = threadIdx.x;
    float c = 1.0f - cum[row];
    ushort4 a = *(const ushort4*)(acc + (size_t)row * Dn + t * 4);
    float4 h = ((const float4*)(hidden + (size_t)row * Dn))[t];
    float vals[4];
    vals[0] = b2f(a.x) + c * h.x; vals[1] = b2f(a.y) + c * h.y;
    vals[2] = b2f(a.z) + c * h.z; vals[3] = b2f(a.w) + c * h.w;
    float s = 0.f, s2 = 0.f;
    #pragma unroll
    for (int i = 0; i < 4; i++) { s += vals[i]; s2 += vals[i]*vals[i]; }
    s  = bsum(s,  sb);
    s2 = bsum(s2, sb);
    float mean = s * (1.f / Dn);
    float var  = s2 * (1.f / Dn) - mean * mean;
    float rstd = rsqrtf(var + EPSc);
    float4 g = ((const float4*)g2)[t];
    float4 bb = ((const float4*)b2)[t];
    float4 o;
    o.x = (vals[0] - mean) * rstd * g.x + bb.x;
    o.y = (vals[1] - mean) * rstd * g.y + bb.y;
    o.z = (vals[2] - mean) * rstd * g.z + bb.z;
    o.w = (vals[3] - mean) * rstd * g.w + bb.w;
    ((float4*)(out + (size_t)row * Dn))[t] = o;
}

extern "C" void kernel_launch(void* const* d_in, const int* in_sizes, int n_in,
                              void* d_out, int out_size, void* d_ws, size_t ws_size,
                              hipStream_t stream) {
    (void)in_sizes; (void)n_in; (void)out_size; (void)ws_size;
    const float* x      = (const float*)d_in[0];
    const float* g1     = (const float*)d_in[1];
    const float* b1     = (const float*)d_in[2];
    const float* W_up   = (const float*)d_in[3];
    const float* b_up   = (const float*)d_in[4];
    const float* W_down = (const float*)d_in[5];
    const float* b_down = (const float*)d_in[6];
    const float* W_halt = (const float*)d_in[7];
    const float* b_halt = (const float*)d_in[8];
    const float* W_comp = (const float*)d_in[9];
    const float* b_comp = (const float*)d_in[10];
    const float* W_attn = (const float*)d_in[11];
    const float* b_attn = (const float*)d_in[12];
    const float* g2     = (const float*)d_in[13];
    const float* b2     = (const float*)d_in[14];
    float* out = (float*)d_out;

    // ws layout — ~257 MB total (< 264.5 MB known-clean)
    char* wsb = (char*)d_ws;
    size_t off = 0;
    float* hidden = (float*)(wsb + off); off += (size_t)Rn * Dn * 4;      // 67.1 MB
    float* hnew   = (float*)(wsb + off); off += (size_t)Rn * Dn * 4;      // 67.1 MB
    bfu*   accb   = (bfu*)  (wsb + off); off += (size_t)Rn * Dn * 2;      // 33.6 MB (bf16)
    f16*   nh     = (f16*)  (wsb + off); off += (size_t)CHUNK * Dn * 2;   //  8.4 MB
    f16*   uh     = (f16*)  (wsb + off); off += (size_t)CHUNK * DIn * 2;  // 33.6 MB
    f16*   pf     = (f16*)  (wsb + off); off += (size_t)3 * CHUNK * Dn * 2; // 25.2 MB (3 f16 split-K partials)
    f16*   WupTh  = (f16*)  (wsb + off); off += (size_t)DIn * Dn * 2;     //  8.4 MB
    f16*   WdnTh  = (f16*)  (wsb + off); off += (size_t)Dn * DIn * 2;     //  8.4 MB
    float* scores = (float*)(wsb + off); off += (size_t)Rn * Mn * 4;      //  0.5 MB
    float* wL     = (float*)(wsb + off); off += (size_t)Rn * Mn * 4;      //  0.5 MB
    float* mpart  = (float*)(wsb + off); off += (size_t)LCH * Bn * Mn * Dn * 4;  // 4.2 MB
    float* memb   = (float*)(wsb + off); off += (size_t)Bn * Mn * Dn * 4; //  0.13 MB
    float* memW   = (float*)(wsb + off); off += (size_t)Bn * Mn * Dn * 4; //  0.13 MB
    float* ent    = (float*)(wsb + off); off += (size_t)Rn * 4;
    float* cum    = (float*)(wsb + off); off += (size_t)Rn * 4;

    transpose_cvt_kernel<<<dim3(DIn / 32, Dn / 32), 256, 0, stream>>>(W_up,   WupTh, Dn, DIn);
    transpose_cvt_kernel<<<dim3(Dn / 32, DIn / 32), 256, 0, stream>>>(W_down, WdnTh, DIn, Dn);

    init_kernel<<<(Rn * Dn / 4) / 256, 256, 0, stream>>>(x, hidden, accb, cum);

    for (int s = 0; s < NSTEP; ++s) {
        for (int c = 0; c < NCH; ++c) {
            ln_ent_kernel<<<CHUNK, 256, 0, stream>>>(
                hidden + (size_t)c * CHUNK * Dn, g1, b1, nh, ent + (size_t)c * CHUNK);
            // up: M=4096, N=4096, K=1024; 1024 blocks, 4 resident/CU
            gemm_f16<0><<<dim3(DIn / 128, CHUNK / 128, 1), 256, 0, stream>>>(
                nh, WupTh, b_up, nullptr, uh, nullptr, DIn, Dn, Dn);
            // down: M=4096, N=1024, K=4096 split z=4; 1024 blocks, 4 resident/CU
            gemm_f16<1><<<dim3(Dn / 128, CHUNK / 128, 4), 256, 0, stream>>>(
                uh, WdnTh, b_down, hidden + (size_t)c * CHUNK * Dn,
                hnew + (size_t)c * CHUNK * Dn, pf, Dn, DIn, DIn / 4);
            add_kernel<<<(CHUNK * Dn / 4) / 256, 256, 0, stream>>>(
                hnew + (size_t)c * CHUNK * Dn, pf);
        }
        scores_kernel<<<Rn, 256, 0, stream>>>(hnew, W_comp, b_comp, scores);
        softmaxL_kernel<<<Bn * Mn, 256, 0, stream>>>(scores, wL);
        memory_kernel<<<Bn * (Dn / 256) * LCH, 256, 0, stream>>>(hnew, wL, mpart);
        memreduce_kernel<<<(Bn * Mn * Dn) / 256, 256, 0, stream>>>(mpart, memb);
        memw_kernel<<<Bn * Mn * 4, 256, 0, stream>>>(memb, W_attn, memW);
        ctx_gate_kernel<<<Rn, 256, 0, stream>>>(scores, memW, b_attn, hnew, hidden,
                                                ent, W_halt, b_halt, accb, cum);
    }

    final_ln_kernel<<<Rn, 256, 0, stream>>>(accb, cum, hidden, g2, b2, out);
}